// Round 7
// baseline (157.936 us; speedup 1.0000x reference)
//
#include <hip/hip_runtime.h>
#include <hip/hip_bf16.h>
#include <cstdint>
#include <cstddef>

#define N_  64
#define L_  196
#define T_  32
#define D_  512
#define LP_ 256                   // l padded to 256 (zero-fill) for MFMA K
#define ROWS1_ (N_ * L_)          // 12544
#define ROWS2_ (N_ * T_)          // 2048
#define NWG1_  ((ROWS1_ / 64) * 4)  // 784  (BM=64, 4 n-tiles)
#define NWG2_  ((ROWS2_ / 64) * 4)  // 128
// total 912 blocks, %8==0

typedef __attribute__((ext_vector_type(8))) short short8;
typedef __attribute__((ext_vector_type(4))) float f32x4;

// f32 -> bf16 bits, round-to-nearest-even
__device__ inline unsigned short f2bf(float f) {
  unsigned u = __builtin_bit_cast(unsigned, f);
  u = u + 0x7FFFu + ((u >> 16) & 1u);
  return (unsigned short)(u >> 16);
}

// ---- fused: bf16 convert of f1/f2 rows + attention dot s = row @ w_att ------
__global__ __launch_bounds__(256)
void cvt_dots(const float* __restrict__ f1, const float* __restrict__ f2,
              const float* __restrict__ w,
              unsigned short* __restrict__ f1b, unsigned short* __restrict__ f2b,
              float* __restrict__ s1, float* __restrict__ s2) {
  int row = blockIdx.x * 4 + (threadIdx.x >> 6);
  int lane = threadIdx.x & 63;
  bool isf1 = row < ROWS1_;
  const float* src = isf1 ? (f1 + (size_t)row * D_) : (f2 + (size_t)(row - ROWS1_) * D_);
  unsigned short* dst = isf1 ? (f1b + (size_t)row * D_) : (f2b + (size_t)(row - ROWS1_) * D_);
  float4 x0 = ((const float4*)src)[lane];
  float4 x1 = ((const float4*)src)[lane + 64];
  float4 w0 = ((const float4*)w)[lane];
  float4 w1 = ((const float4*)w)[lane + 64];
  float d = x0.x * w0.x + x0.y * w0.y + x0.z * w0.z + x0.w * w0.w
          + x1.x * w1.x + x1.y * w1.y + x1.z * w1.z + x1.w * w1.w;
  ushort4 o0, o1;
  o0.x = f2bf(x0.x); o0.y = f2bf(x0.y); o0.z = f2bf(x0.z); o0.w = f2bf(x0.w);
  o1.x = f2bf(x1.x); o1.y = f2bf(x1.y); o1.z = f2bf(x1.z); o1.w = f2bf(x1.w);
  ((ushort4*)dst)[lane] = o0;
  ((ushort4*)dst)[lane + 64] = o1;
  #pragma unroll
  for (int s = 32; s; s >>= 1) d += __shfl_xor(d, s);
  if (lane == 0) {
    if (isf1) s1[row] = d; else s2[row - ROWS1_] = d;
  }
}

// ------------- weight transpose + convert: Wt[n][k] = bf16(W[k][n]) -----------
__global__ __launch_bounds__(256)
void wt_cvt(const float* __restrict__ w0, const float* __restrict__ w1,
            const float* __restrict__ w2, const float* __restrict__ w3,
            unsigned short* __restrict__ o0, unsigned short* __restrict__ o1,
            unsigned short* __restrict__ o2, unsigned short* __restrict__ o3) {
  const float* W = (blockIdx.y == 0) ? w0 : (blockIdx.y == 1) ? w1 : (blockIdx.y == 2) ? w2 : w3;
  unsigned short* O = (blockIdx.y == 0) ? o0 : (blockIdx.y == 1) ? o1 : (blockIdx.y == 2) ? o2 : o3;
  int k0 = (blockIdx.x >> 3) * 64, n0 = (blockIdx.x & 7) * 64;
  __shared__ float tl[64][65];
  int t = threadIdx.x;
  #pragma unroll
  for (int i = 0; i < 16; i++) {
    int e = t + i * 256;
    int r = e >> 6, c = e & 63;
    tl[r][c] = W[(size_t)(k0 + r) * D_ + n0 + c];
  }
  __syncthreads();
  #pragma unroll
  for (int i = 0; i < 16; i++) {
    int e = t + i * 256;
    int r = e >> 6, c = e & 63;
    O[(size_t)(n0 + r) * D_ + k0 + c] = f2bf(tl[c][r]);
  }
}

// -------- f1 transpose (bf16 src): f1t[n][d][l] = f1b[n][l][d], l pad 256 ----
// grid: n(64) x lchunk(4) x dchunk(8) = 2048 blocks; ushort4 both directions
__global__ __launch_bounds__(256)
void f1t_cvt(const unsigned short* __restrict__ f1b, unsigned short* __restrict__ f1t) {
  int bi = blockIdx.x;
  int n = bi >> 5, rem = bi & 31;
  int l0 = (rem >> 3) * 64, d0 = (rem & 7) * 64;
  __shared__ unsigned short tl[64][72];   // pad 72 to break bank alignment
  int t = threadIdx.x;
  #pragma unroll
  for (int i = 0; i < 4; i++) {
    int e = t + i * 256;            // 1024 ushort4 per tile
    int r = e >> 4, c4 = e & 15;    // r = l-within-tile, c4 = d-group
    int l = l0 + r;
    ushort4 v;
    if (l < L_) v = *(const ushort4*)&f1b[((size_t)n * L_ + l) * D_ + d0 + c4 * 4];
    else { v.x = 0; v.y = 0; v.z = 0; v.w = 0; }
    *(ushort4*)&tl[r][c4 * 4] = v;
  }
  __syncthreads();
  #pragma unroll
  for (int i = 0; i < 4; i++) {
    int e = t + i * 256;
    int r = e >> 4, c4 = e & 15;    // r = d-within-tile, c4 = l-group
    ushort4 o;
    o.x = tl[c4 * 4 + 0][r];
    o.y = tl[c4 * 4 + 1][r];
    o.z = tl[c4 * 4 + 2][r];
    o.w = tl[c4 * 4 + 3][r];
    *(ushort4*)&f1t[((size_t)n * D_ + d0 + r) * LP_ + l0 + c4 * 4] = o;
  }
}

// ------ softmax over L per (n,t): writes f32 att (output) + bf16 att_b -------
__global__ __launch_bounds__(64)
void softmax_att(const float* __restrict__ s1, const float* __restrict__ s2,
                 const float* __restrict__ b_att, float* __restrict__ att,
                 unsigned short* __restrict__ attb) {
  int b = blockIdx.x;           // n*32 + t
  int n = b >> 5;
  int lane = threadIdx.x;
  float s2v = s2[b] + b_att[0];
  const float* s1n = s1 + (size_t)n * L_;
  float v[4];
  float mx = -1e30f;
  #pragma unroll
  for (int j = 0; j < 4; j++) {
    int l = lane + j * 64;
    v[j] = (l < L_) ? (s1n[l] + s2v) : -1e30f;
    mx = fmaxf(mx, v[j]);
  }
  #pragma unroll
  for (int s = 32; s; s >>= 1) mx = fmaxf(mx, __shfl_xor(mx, s));
  float sum = 0.f;
  #pragma unroll
  for (int j = 0; j < 4; j++) { v[j] = __expf(v[j] - mx); sum += v[j]; }
  #pragma unroll
  for (int s = 32; s; s >>= 1) sum += __shfl_xor(sum, s);
  float inv = 1.f / sum;
  float* an = att + (size_t)b * L_;
  unsigned short* ab = attb + (size_t)b * LP_;
  #pragma unroll
  for (int j = 0; j < 4; j++) {
    int l = lane + j * 64;
    float p = v[j] * inv;
    if (l < L_) an[l] = p;
    ab[l] = (l < L_) ? f2bf(p) : (unsigned short)0;   // zero K-pad
  }
}

// -------- fused GLU GEMM (both problems, one grid) ---------------------------
// BM=64, BN=128, BK=32; 912 blocks, 4 waves (2x2), wave tile 32x64.
// LDS 40KB -> up to 4 blocks/CU; 3.56 blocks/CU avg hides the barrier drain.
__global__ __launch_bounds__(256, 3)
void glu_gemm(const unsigned short* __restrict__ Xb1, const unsigned short* __restrict__ Xb2,
              const unsigned short* __restrict__ W1t_1, const unsigned short* __restrict__ W2t_1,
              const unsigned short* __restrict__ W1t_2, const unsigned short* __restrict__ W2t_2,
              const float* __restrict__ b1_1, const float* __restrict__ b2_1,
              const float* __restrict__ b1_2, const float* __restrict__ b2_2,
              float* __restrict__ o1, float* __restrict__ o0) {
  int nwg = gridDim.x;
  int q = nwg >> 3;                         // nwg % 8 == 0 by construction
  int orig = blockIdx.x;
  int bid = (orig & 7) * q + (orig >> 3);   // XCD-chunked swizzle (bijective)
  const unsigned short *Xb, *W1t, *W2t;
  const float *b1, *b2;
  float* out;
  if (bid < NWG1_) { Xb = Xb1; W1t = W1t_1; W2t = W2t_1; b1 = b1_1; b2 = b2_1; out = o1; }
  else { bid -= NWG1_; Xb = Xb2; W1t = W1t_2; W2t = W2t_2; b1 = b1_2; b2 = b2_2; out = o0; }
  int nt = bid & 3, mt = bid >> 2;
  int m0 = mt * 64, n0 = nt * 128;
  int t = threadIdx.x, lane = t & 63, wave = t >> 6;
  int wr = (wave >> 1) * 32, wc = (wave & 1) * 64;

  __shared__ alignas(16) unsigned short Xs[2][2048];      // [64][32]
  __shared__ alignas(16) unsigned short Ws[2][2][4096];   // [mat][128][32]

  auto stage = [&](int buf, int k0) {
    {
      int c = t;                                // 256 chunks of 16B: X tile
      const unsigned short* g = Xb + (size_t)(m0 + (c >> 2)) * D_ + k0 + (c & 3) * 8;
      unsigned short* l = &Xs[buf][(size_t)wave * 512];
      __builtin_amdgcn_global_load_lds((const __attribute__((address_space(1))) unsigned int*)g,
                                       (__attribute__((address_space(3))) unsigned int*)l,
                                       16, 0, 0);
    }
    #pragma unroll
    for (int w = 0; w < 2; w++) {
      const unsigned short* Wt = w ? W2t : W1t;
      #pragma unroll
      for (int i = 0; i < 2; i++) {
        int c = t + i * 256;                    // 512 chunks: W tile
        const unsigned short* g = Wt + (size_t)(n0 + (c >> 2)) * D_ + k0 + (c & 3) * 8;
        unsigned short* l = &Ws[buf][w][(size_t)(wave * 64 + i * 256) * 8];
        __builtin_amdgcn_global_load_lds((const __attribute__((address_space(1))) unsigned int*)g,
                                         (__attribute__((address_space(3))) unsigned int*)l,
                                         16, 0, 0);
      }
    }
  };

  f32x4 acc1[2][4], acc2[2][4];
  #pragma unroll
  for (int i = 0; i < 2; i++)
    #pragma unroll
    for (int j = 0; j < 4; j++) { acc1[i][j] = (f32x4)(0.f); acc2[i][j] = (f32x4)(0.f); }

  stage(0, 0);
  int cur = 0;
  int arow = lane & 15, ak = (lane >> 4) * 8;
  for (int ks = 0; ks < 16; ++ks) {
    __syncthreads();
    if (ks < 15) stage(cur ^ 1, (ks + 1) * 32);
    short8 a[2], bf1[4], bf2[4];
    #pragma unroll
    for (int mf = 0; mf < 2; mf++)
      a[mf] = *(const short8*)&Xs[cur][(wr + mf * 16 + arow) * 32 + ak];
    #pragma unroll
    for (int nf = 0; nf < 4; nf++) {
      bf1[nf] = *(const short8*)&Ws[cur][0][(wc + nf * 16 + arow) * 32 + ak];
      bf2[nf] = *(const short8*)&Ws[cur][1][(wc + nf * 16 + arow) * 32 + ak];
    }
    #pragma unroll
    for (int mf = 0; mf < 2; mf++)
      #pragma unroll
      for (int nf = 0; nf < 4; nf++) {
        acc1[mf][nf] = __builtin_amdgcn_mfma_f32_16x16x32_bf16(a[mf], bf1[nf], acc1[mf][nf], 0, 0, 0);
        acc2[mf][nf] = __builtin_amdgcn_mfma_f32_16x16x32_bf16(a[mf], bf2[nf], acc2[mf][nf], 0, 0, 0);
      }
    cur ^= 1;
  }

  // epilogue: C/D layout col=lane&15, row=(lane>>4)*4+r  [m89-verified]
  int crow = (lane >> 4) * 4, ccol = lane & 15;
  #pragma unroll
  for (int mf = 0; mf < 2; mf++) {
    #pragma unroll
    for (int nf = 0; nf < 4; nf++) {
      int col = n0 + wc + nf * 16 + ccol;
      float bb1 = b1[col], bb2 = b2[col];
      #pragma unroll
      for (int r = 0; r < 4; r++) {
        int row = m0 + wr + mf * 16 + crow + r;
        float z1 = acc1[mf][nf][r] + bb1;
        float z2 = acc2[mf][nf][r] + bb2;
        float th = 1.f - 2.f / (__expf(2.f * z1) + 1.f);
        float sg = 1.f / (1.f + __expf(-z2));
        out[(size_t)row * D_ + col] = th * sg;
      }
    }
  }
}

// -------- f_hat via MFMA: out0[n] += att_b[n] (32x256) @ f1t[n]^T (256x512) --
__global__ __launch_bounds__(256)
void fhat_mfma(const unsigned short* __restrict__ attb,   // [64][32][256]
               const unsigned short* __restrict__ f1t,    // [64][512][256]
               float* __restrict__ out0) {                // [64][32][512]
  int n = blockIdx.x >> 2, dq = blockIdx.x & 3;
  int lane = threadIdx.x & 63, wave = threadIdx.x >> 6;
  int d0 = dq * 128 + wave * 32;
  int arow = lane & 15, ak = (lane >> 4) * 8;
  const unsigned short* A = attb + (size_t)n * T_ * LP_;
  const unsigned short* B = f1t + ((size_t)n * D_ + d0) * LP_;
  f32x4 acc[2][2];
  #pragma unroll
  for (int i = 0; i < 2; i++)
    #pragma unroll
    for (int j = 0; j < 2; j++) acc[i][j] = (f32x4)(0.f);
  #pragma unroll 2
  for (int kk = 0; kk < 8; kk++) {
    int k0 = kk * 32;
    short8 a[2], b[2];
    #pragma unroll
    for (int mt = 0; mt < 2; mt++)
      a[mt] = *(const short8*)&A[(size_t)(mt * 16 + arow) * LP_ + k0 + ak];
    #pragma unroll
    for (int nt2 = 0; nt2 < 2; nt2++)
      b[nt2] = *(const short8*)&B[(size_t)(nt2 * 16 + arow) * LP_ + k0 + ak];
    #pragma unroll
    for (int mt = 0; mt < 2; mt++)
      #pragma unroll
      for (int nt2 = 0; nt2 < 2; nt2++)
        acc[mt][nt2] = __builtin_amdgcn_mfma_f32_16x16x32_bf16(a[mt], b[nt2], acc[mt][nt2], 0, 0, 0);
  }
  int crow = (lane >> 4) * 4, ccol = lane & 15;
  #pragma unroll
  for (int mt = 0; mt < 2; mt++) {
    #pragma unroll
    for (int nt2 = 0; nt2 < 2; nt2++) {
      int d = d0 + nt2 * 16 + ccol;
      #pragma unroll
      for (int r = 0; r < 4; r++) {
        int tt = mt * 16 + crow + r;
        size_t idx = ((size_t)n * T_ + tt) * D_ + d;
        out0[idx] += acc[mt][nt2][r];
      }
    }
  }
}

extern "C" void kernel_launch(void* const* d_in, const int* in_sizes, int n_in,
                              void* d_out, int out_size, void* d_ws, size_t ws_size,
                              hipStream_t stream) {
  const float* f1    = (const float*)d_in[0];
  const float* f2    = (const float*)d_in[1];
  const float* w_att = (const float*)d_in[2];
  const float* b_att = (const float*)d_in[3];
  const float* n1w1  = (const float*)d_in[4];
  const float* n1b1  = (const float*)d_in[5];
  const float* n1w2  = (const float*)d_in[6];
  const float* n1b2  = (const float*)d_in[7];
  const float* n2w1  = (const float*)d_in[8];
  const float* n2b1  = (const float*)d_in[9];
  const float* n2w2  = (const float*)d_in[10];
  const float* n2b2  = (const float*)d_in[11];

  float* out0 = (float*)d_out;                        // [64][32][512]
  float* out1 = out0 + (size_t)N_ * T_ * D_;          // [64][196][512]
  float* att  = out1 + (size_t)N_ * L_ * D_;          // [64][32][196]

  char* ws = (char*)d_ws;
  auto alloc = [&](size_t bytes) { char* p = ws; ws += (bytes + 255) & ~(size_t)255; return p; };
  unsigned short* f1b   = (unsigned short*)alloc((size_t)ROWS1_ * D_ * 2);
  unsigned short* f2b   = (unsigned short*)alloc((size_t)ROWS2_ * D_ * 2);
  unsigned short* w1t_1 = (unsigned short*)alloc((size_t)D_ * D_ * 2);
  unsigned short* w2t_1 = (unsigned short*)alloc((size_t)D_ * D_ * 2);
  unsigned short* w1t_2 = (unsigned short*)alloc((size_t)D_ * D_ * 2);
  unsigned short* w2t_2 = (unsigned short*)alloc((size_t)D_ * D_ * 2);
  unsigned short* f1t   = (unsigned short*)alloc((size_t)N_ * D_ * LP_ * 2);  // 16.8 MB
  unsigned short* attb  = (unsigned short*)alloc((size_t)N_ * T_ * LP_ * 2);  // 1.05 MB
  float* s1 = (float*)alloc((size_t)ROWS1_ * 4);
  float* s2 = (float*)alloc((size_t)ROWS2_ * 4);

  cvt_dots<<<(ROWS1_ + ROWS2_) / 4, 256, 0, stream>>>(f1, f2, w_att, f1b, f2b, s1, s2);
  wt_cvt<<<dim3(64, 4), 256, 0, stream>>>(n1w1, n1w2, n2w1, n2w2, w1t_1, w2t_1, w1t_2, w2t_2);
  glu_gemm<<<NWG1_ + NWG2_, 256, 0, stream>>>(f1b, f2b, w1t_1, w2t_1, w1t_2, w2t_2,
                                              n1b1, n1b2, n2b1, n2b2, out1, out0);
  f1t_cvt<<<N_ * 32, 256, 0, stream>>>(f1b, f1t);
  softmax_att<<<N_ * T_, 64, 0, stream>>>(s1, s2, b_att, att, attb);
  fhat_mfma<<<N_ * 4, 256, 0, stream>>>(attb, f1t, out0);
}

// Round 8
// 144.817 us; speedup vs baseline: 1.0906x; 1.0906x over previous
//
#include <hip/hip_runtime.h>
#include <hip/hip_bf16.h>
#include <cstdint>
#include <cstddef>

#define N_  64
#define L_  196
#define T_  32
#define D_  512
#define ROWS1_ (N_ * L_)            // 12544
#define ROWS2_ (N_ * T_)            // 2048
#define NWG1_  ((ROWS1_ / 64) * 4)  // 784  (BM=64, 4 n-tiles)
#define NWG2_  ((ROWS2_ / 64) * 4)  // 128  -> 912 total, %8==0
#define CVTB_  ((ROWS1_ + ROWS2_) / 4)  // 3648 prep blocks for cvt part
#define BSTR   264                  // LDS row stride (ushorts): 528B, 16B-aligned

typedef __attribute__((ext_vector_type(8))) short short8;
typedef __attribute__((ext_vector_type(4))) float f32x4;

// f32 -> bf16 bits, round-to-nearest-even
__device__ inline unsigned short f2bf(float f) {
  unsigned u = __builtin_bit_cast(unsigned, f);
  u = u + 0x7FFFu + ((u >> 16) & 1u);
  return (unsigned short)(u >> 16);
}

// ---- prep: [blocks 0..3647] bf16 convert + att dot; [3648..3903] weight T ----
__global__ __launch_bounds__(256)
void prep(const float* __restrict__ f1, const float* __restrict__ f2,
          const float* __restrict__ w,
          const float* __restrict__ w0, const float* __restrict__ w1,
          const float* __restrict__ w2, const float* __restrict__ w3,
          unsigned short* __restrict__ f1b, unsigned short* __restrict__ f2b,
          float* __restrict__ s1, float* __restrict__ s2,
          unsigned short* __restrict__ o0, unsigned short* __restrict__ o1,
          unsigned short* __restrict__ o2, unsigned short* __restrict__ o3) {
  __shared__ float tl[64][65];
  int t = threadIdx.x;
  if (blockIdx.x < CVTB_) {
    int row = blockIdx.x * 4 + (t >> 6);
    int lane = t & 63;
    bool isf1 = row < ROWS1_;
    const float* src = isf1 ? (f1 + (size_t)row * D_) : (f2 + (size_t)(row - ROWS1_) * D_);
    unsigned short* dst = isf1 ? (f1b + (size_t)row * D_) : (f2b + (size_t)(row - ROWS1_) * D_);
    float4 x0 = ((const float4*)src)[lane];
    float4 x1 = ((const float4*)src)[lane + 64];
    float4 ww0 = ((const float4*)w)[lane];
    float4 ww1 = ((const float4*)w)[lane + 64];
    float d = x0.x * ww0.x + x0.y * ww0.y + x0.z * ww0.z + x0.w * ww0.w
            + x1.x * ww1.x + x1.y * ww1.y + x1.z * ww1.z + x1.w * ww1.w;
    ushort4 b0, b1v;
    b0.x = f2bf(x0.x); b0.y = f2bf(x0.y); b0.z = f2bf(x0.z); b0.w = f2bf(x0.w);
    b1v.x = f2bf(x1.x); b1v.y = f2bf(x1.y); b1v.z = f2bf(x1.z); b1v.w = f2bf(x1.w);
    ((ushort4*)dst)[lane] = b0;
    ((ushort4*)dst)[lane + 64] = b1v;
    #pragma unroll
    for (int s = 32; s; s >>= 1) d += __shfl_xor(d, s);
    if (lane == 0) {
      if (isf1) s1[row] = d; else s2[row - ROWS1_] = d;
    }
  } else {
    int b2 = blockIdx.x - CVTB_;            // 0..255
    int which = b2 >> 6, tile = b2 & 63;
    const float* W = (which == 0) ? w0 : (which == 1) ? w1 : (which == 2) ? w2 : w3;
    unsigned short* O = (which == 0) ? o0 : (which == 1) ? o1 : (which == 2) ? o2 : o3;
    int k0 = (tile >> 3) * 64, n0 = (tile & 7) * 64;
    #pragma unroll
    for (int i = 0; i < 16; i++) {
      int e = t + i * 256;
      int r = e >> 6, c = e & 63;
      tl[r][c] = W[(size_t)(k0 + r) * D_ + n0 + c];
    }
    __syncthreads();
    #pragma unroll
    for (int i = 0; i < 16; i++) {
      int e = t + i * 256;
      int r = e >> 6, c = e & 63;
      O[(size_t)(n0 + r) * D_ + k0 + c] = f2bf(tl[c][r]);
    }
  }
}

// -------- fused GLU GEMM (both problems, one grid) ---------------------------
// BM=64, BN=128, BK=32; 912 blocks, 4 waves (2x2), wave tile 32x64.
__global__ __launch_bounds__(256, 3)
void glu_gemm(const unsigned short* __restrict__ Xb1, const unsigned short* __restrict__ Xb2,
              const unsigned short* __restrict__ W1t_1, const unsigned short* __restrict__ W2t_1,
              const unsigned short* __restrict__ W1t_2, const unsigned short* __restrict__ W2t_2,
              const float* __restrict__ b1_1, const float* __restrict__ b2_1,
              const float* __restrict__ b1_2, const float* __restrict__ b2_2,
              float* __restrict__ o1, float* __restrict__ o0) {
  int nwg = gridDim.x;
  int q = nwg >> 3;                         // nwg % 8 == 0 by construction
  int orig = blockIdx.x;
  int bid = (orig & 7) * q + (orig >> 3);   // XCD-chunked swizzle (bijective)
  const unsigned short *Xb, *W1t, *W2t;
  const float *b1, *b2;
  float* out;
  if (bid < NWG1_) { Xb = Xb1; W1t = W1t_1; W2t = W2t_1; b1 = b1_1; b2 = b2_1; out = o1; }
  else { bid -= NWG1_; Xb = Xb2; W1t = W1t_2; W2t = W2t_2; b1 = b1_2; b2 = b2_2; out = o0; }
  int nt = bid & 3, mt = bid >> 2;
  int m0 = mt * 64, n0 = nt * 128;
  int t = threadIdx.x, lane = t & 63, wave = t >> 6;
  int wr = (wave >> 1) * 32, wc = (wave & 1) * 64;

  __shared__ alignas(16) unsigned short Xs[2][2048];      // [64][32]
  __shared__ alignas(16) unsigned short Ws[2][2][4096];   // [mat][128][32]

  auto stage = [&](int buf, int k0) {
    {
      int c = t;                                // 256 chunks of 16B: X tile
      const unsigned short* g = Xb + (size_t)(m0 + (c >> 2)) * D_ + k0 + (c & 3) * 8;
      unsigned short* l = &Xs[buf][(size_t)wave * 512];
      __builtin_amdgcn_global_load_lds((const __attribute__((address_space(1))) unsigned int*)g,
                                       (__attribute__((address_space(3))) unsigned int*)l,
                                       16, 0, 0);
    }
    #pragma unroll
    for (int w = 0; w < 2; w++) {
      const unsigned short* Wt = w ? W2t : W1t;
      #pragma unroll
      for (int i = 0; i < 2; i++) {
        int c = t + i * 256;                    // 512 chunks: W tile
        const unsigned short* g = Wt + (size_t)(n0 + (c >> 2)) * D_ + k0 + (c & 3) * 8;
        unsigned short* l = &Ws[buf][w][(size_t)(wave * 64 + i * 256) * 8];
        __builtin_amdgcn_global_load_lds((const __attribute__((address_space(1))) unsigned int*)g,
                                         (__attribute__((address_space(3))) unsigned int*)l,
                                         16, 0, 0);
      }
    }
  };

  f32x4 acc1[2][4], acc2[2][4];
  #pragma unroll
  for (int i = 0; i < 2; i++)
    #pragma unroll
    for (int j = 0; j < 4; j++) { acc1[i][j] = (f32x4)(0.f); acc2[i][j] = (f32x4)(0.f); }

  stage(0, 0);
  int cur = 0;
  int arow = lane & 15, ak = (lane >> 4) * 8;
  for (int ks = 0; ks < 16; ++ks) {
    __syncthreads();
    if (ks < 15) stage(cur ^ 1, (ks + 1) * 32);
    short8 a[2], bf1[4], bf2[4];
    #pragma unroll
    for (int mf = 0; mf < 2; mf++)
      a[mf] = *(const short8*)&Xs[cur][(wr + mf * 16 + arow) * 32 + ak];
    #pragma unroll
    for (int nf = 0; nf < 4; nf++) {
      bf1[nf] = *(const short8*)&Ws[cur][0][(wc + nf * 16 + arow) * 32 + ak];
      bf2[nf] = *(const short8*)&Ws[cur][1][(wc + nf * 16 + arow) * 32 + ak];
    }
    #pragma unroll
    for (int mf = 0; mf < 2; mf++)
      #pragma unroll
      for (int nf = 0; nf < 4; nf++) {
        acc1[mf][nf] = __builtin_amdgcn_mfma_f32_16x16x32_bf16(a[mf], bf1[nf], acc1[mf][nf], 0, 0, 0);
        acc2[mf][nf] = __builtin_amdgcn_mfma_f32_16x16x32_bf16(a[mf], bf2[nf], acc2[mf][nf], 0, 0, 0);
      }
    cur ^= 1;
  }

  // epilogue: C/D layout col=lane&15, row=(lane>>4)*4+r  [m89-verified]
  int crow = (lane >> 4) * 4, ccol = lane & 15;
  #pragma unroll
  for (int mf = 0; mf < 2; mf++) {
    #pragma unroll
    for (int nf = 0; nf < 4; nf++) {
      int col = n0 + wc + nf * 16 + ccol;
      float bb1 = b1[col], bb2 = b2[col];
      #pragma unroll
      for (int r = 0; r < 4; r++) {
        int row = m0 + wr + mf * 16 + crow + r;
        float z1 = acc1[mf][nf][r] + bb1;
        float z2 = acc2[mf][nf][r] + bb2;
        float th = 1.f - 2.f / (__expf(2.f * z1) + 1.f);
        float sg = 1.f / (1.f + __expf(-z2));
        out[(size_t)row * D_ + col] = th * sg;
      }
    }
  }
}

// ---- fhat_fused: softmax + LDS transpose + MFMA, out0 += att @ f1 -----------
// grid = n(64) x dq(4) = 256 blocks, 4 waves. Block handles d = dq*128..+127.
// Bs[d][l] = f1b[n][l][d0+d] (transposed in LDS); Ps[t][l] = bf16 softmax row.
__global__ __launch_bounds__(256)
void fhat_fused(const float* __restrict__ s1, const float* __restrict__ s2,
                const float* __restrict__ b_att,
                const unsigned short* __restrict__ f1b,
                float* __restrict__ att, float* __restrict__ out0) {
  int n = blockIdx.x >> 2, dq = blockIdx.x & 3;
  int d0 = dq * 128;
  int t = threadIdx.x, lane = t & 63, wave = t >> 6;
  __shared__ unsigned short Ps[32 * BSTR];    // 16.9 KB
  __shared__ unsigned short Bs[128 * BSTR];   // 67.6 KB

  // Phase B1: zero-pad Bs l in [196, 264) (ushort4, disjoint from data writes)
  for (int e = t; e < 128 * 17; e += 256) {
    int d = e / 17, qq = e % 17;
    ushort4 z; z.x = 0; z.y = 0; z.z = 0; z.w = 0;
    *(ushort4*)&Bs[d * BSTR + 196 + qq * 4] = z;
  }
  // Phase B2: transposed stage of f1b[n][l][d0..d0+127]
  {
    int c4 = t & 31;            // d-group of 4
    int lr = t >> 5;            // 0..7
    #pragma unroll
    for (int i = 0; i < 25; i++) {
      int l = i * 8 + lr;
      if (l < L_) {
        ushort4 v = *(const ushort4*)&f1b[((size_t)n * L_ + l) * D_ + d0 + c4 * 4];
        Bs[(c4 * 4 + 0) * BSTR + l] = v.x;
        Bs[(c4 * 4 + 1) * BSTR + l] = v.y;
        Bs[(c4 * 4 + 2) * BSTR + l] = v.z;
        Bs[(c4 * 4 + 3) * BSTR + l] = v.w;
      }
    }
  }
  // Phase A: softmax for this n (8 lanes per row; rows t = wave*8 + lane/8)
  {
    int trow = wave * 8 + (lane >> 3);
    int j = lane & 7;
    float s2v = s2[n * T_ + trow] + b_att[0];
    const float* s1n = s1 + (size_t)n * L_;
    float v[25];
    float mx = -1e30f;
    #pragma unroll
    for (int i = 0; i < 25; i++) {
      int l = j + 8 * i;
      v[i] = (l < L_) ? (s1n[l] + s2v) : -1e30f;
      mx = fmaxf(mx, v[i]);
    }
    mx = fmaxf(mx, __shfl_xor(mx, 1));
    mx = fmaxf(mx, __shfl_xor(mx, 2));
    mx = fmaxf(mx, __shfl_xor(mx, 4));
    float sum = 0.f;
    #pragma unroll
    for (int i = 0; i < 25; i++) { v[i] = __expf(v[i] - mx); sum += v[i]; }
    sum += __shfl_xor(sum, 1);
    sum += __shfl_xor(sum, 2);
    sum += __shfl_xor(sum, 4);
    float inv = 1.f / sum;
    float* an = att + ((size_t)n * T_ + trow) * L_;
    #pragma unroll
    for (int i = 0; i < 32; i++) {            // l = j+8i covers 0..255
      int l = j + 8 * i;
      float p = (i < 25) ? v[i] * inv : 0.f;
      bool valid = l < L_;
      Ps[trow * BSTR + l] = valid ? f2bf(p) : (unsigned short)0;
      if (dq == 0 && valid) an[l] = p;
    }
  }
  __syncthreads();

  // Phase C: MFMA  C[t][d] += sum_l P[t][l] * Bs[d][l]
  int d0w = wave * 32;
  int arow = lane & 15, ak = (lane >> 4) * 8;
  f32x4 acc[2][2];
  #pragma unroll
  for (int i = 0; i < 2; i++)
    #pragma unroll
    for (int j = 0; j < 2; j++) acc[i][j] = (f32x4)(0.f);
  #pragma unroll 2
  for (int kk = 0; kk < 8; kk++) {
    int k0 = kk * 32;
    short8 a[2], b[2];
    #pragma unroll
    for (int mt = 0; mt < 2; mt++)
      a[mt] = *(const short8*)&Ps[(mt * 16 + arow) * BSTR + k0 + ak];
    #pragma unroll
    for (int nt2 = 0; nt2 < 2; nt2++)
      b[nt2] = *(const short8*)&Bs[(d0w + nt2 * 16 + arow) * BSTR + k0 + ak];
    #pragma unroll
    for (int mt = 0; mt < 2; mt++)
      #pragma unroll
      for (int nt2 = 0; nt2 < 2; nt2++)
        acc[mt][nt2] = __builtin_amdgcn_mfma_f32_16x16x32_bf16(a[mt], b[nt2], acc[mt][nt2], 0, 0, 0);
  }
  int crow = (lane >> 4) * 4, ccol = lane & 15;
  #pragma unroll
  for (int mt = 0; mt < 2; mt++) {
    #pragma unroll
    for (int nt2 = 0; nt2 < 2; nt2++) {
      int d = d0 + d0w + nt2 * 16 + ccol;
      #pragma unroll
      for (int r = 0; r < 4; r++) {
        int tt = mt * 16 + crow + r;
        size_t idx = ((size_t)n * T_ + tt) * D_ + d;
        out0[idx] += acc[mt][nt2][r];
      }
    }
  }
}

extern "C" void kernel_launch(void* const* d_in, const int* in_sizes, int n_in,
                              void* d_out, int out_size, void* d_ws, size_t ws_size,
                              hipStream_t stream) {
  const float* f1    = (const float*)d_in[0];
  const float* f2    = (const float*)d_in[1];
  const float* w_att = (const float*)d_in[2];
  const float* b_att = (const float*)d_in[3];
  const float* n1w1  = (const float*)d_in[4];
  const float* n1b1  = (const float*)d_in[5];
  const float* n1w2  = (const float*)d_in[6];
  const float* n1b2  = (const float*)d_in[7];
  const float* n2w1  = (const float*)d_in[8];
  const float* n2b1  = (const float*)d_in[9];
  const float* n2w2  = (const float*)d_in[10];
  const float* n2b2  = (const float*)d_in[11];

  float* out0 = (float*)d_out;                        // [64][32][512]
  float* out1 = out0 + (size_t)N_ * T_ * D_;          // [64][196][512]
  float* att  = out1 + (size_t)N_ * L_ * D_;          // [64][32][196]

  char* ws = (char*)d_ws;
  auto alloc = [&](size_t bytes) { char* p = ws; ws += (bytes + 255) & ~(size_t)255; return p; };
  unsigned short* f1b   = (unsigned short*)alloc((size_t)ROWS1_ * D_ * 2);
  unsigned short* f2b   = (unsigned short*)alloc((size_t)ROWS2_ * D_ * 2);
  unsigned short* w1t_1 = (unsigned short*)alloc((size_t)D_ * D_ * 2);
  unsigned short* w2t_1 = (unsigned short*)alloc((size_t)D_ * D_ * 2);
  unsigned short* w1t_2 = (unsigned short*)alloc((size_t)D_ * D_ * 2);
  unsigned short* w2t_2 = (unsigned short*)alloc((size_t)D_ * D_ * 2);
  float* s1 = (float*)alloc((size_t)ROWS1_ * 4);
  float* s2 = (float*)alloc((size_t)ROWS2_ * 4);

  prep<<<CVTB_ + 256, 256, 0, stream>>>(f1, f2, w_att, n1w1, n1w2, n2w1, n2w2,
                                        f1b, f2b, s1, s2,
                                        w1t_1, w2t_1, w1t_2, w2t_2);
  glu_gemm<<<NWG1_ + NWG2_, 256, 0, stream>>>(f1b, f2b, w1t_1, w2t_1, w1t_2, w2t_2,
                                              n1b1, n1b2, n2b1, n2b2, out1, out0);
  fhat_fused<<<N_ * 4, 256, 0, stream>>>(s1, s2, b_att, f1b, att, out0);
}

// Round 10
// 143.254 us; speedup vs baseline: 1.1025x; 1.0109x over previous
//
#include <hip/hip_runtime.h>
#include <hip/hip_bf16.h>
#include <cstdint>
#include <cstddef>

#define N_  64
#define L_  196
#define T_  32
#define D_  512
#define ROWS1_ (N_ * L_)            // 12544
#define ROWS2_ (N_ * T_)            // 2048
#define NWG1_  ((ROWS1_ / 64) * 4)  // 784  (BM=64, 4 n-tiles)
#define NWG2_  ((ROWS2_ / 64) * 4)  // 128  -> 912 total, %8==0
#define CVTB_  ((ROWS1_ + ROWS2_) / 4)  // 3648 prep blocks for cvt part
#define BSTR   264                  // LDS row stride (ushorts): 528B, 16B-aligned

typedef __attribute__((ext_vector_type(8))) short short8;
typedef __attribute__((ext_vector_type(4))) float f32x4;

// f32 -> bf16 bits, round-to-nearest-even
__device__ inline unsigned short f2bf(float f) {
  unsigned u = __builtin_bit_cast(unsigned, f);
  u = u + 0x7FFFu + ((u >> 16) & 1u);
  return (unsigned short)(u >> 16);
}

// ---- prep: [blocks 0..3647] bf16 convert + att dot; [3648..3903] weight T ----
__global__ __launch_bounds__(256)
void prep(const float* __restrict__ f1, const float* __restrict__ f2,
          const float* __restrict__ w,
          const float* __restrict__ w0, const float* __restrict__ w1,
          const float* __restrict__ w2, const float* __restrict__ w3,
          unsigned short* __restrict__ f1b, unsigned short* __restrict__ f2b,
          float* __restrict__ s1, float* __restrict__ s2,
          unsigned short* __restrict__ o0, unsigned short* __restrict__ o1,
          unsigned short* __restrict__ o2, unsigned short* __restrict__ o3) {
  __shared__ float tl[64][65];
  int t = threadIdx.x;
  if (blockIdx.x < CVTB_) {
    int row = blockIdx.x * 4 + (t >> 6);
    int lane = t & 63;
    bool isf1 = row < ROWS1_;
    const float* src = isf1 ? (f1 + (size_t)row * D_) : (f2 + (size_t)(row - ROWS1_) * D_);
    unsigned short* dst = isf1 ? (f1b + (size_t)row * D_) : (f2b + (size_t)(row - ROWS1_) * D_);
    float4 x0 = ((const float4*)src)[lane];
    float4 x1 = ((const float4*)src)[lane + 64];
    float4 ww0 = ((const float4*)w)[lane];
    float4 ww1 = ((const float4*)w)[lane + 64];
    float d = x0.x * ww0.x + x0.y * ww0.y + x0.z * ww0.z + x0.w * ww0.w
            + x1.x * ww1.x + x1.y * ww1.y + x1.z * ww1.z + x1.w * ww1.w;
    ushort4 b0, b1v;
    b0.x = f2bf(x0.x); b0.y = f2bf(x0.y); b0.z = f2bf(x0.z); b0.w = f2bf(x0.w);
    b1v.x = f2bf(x1.x); b1v.y = f2bf(x1.y); b1v.z = f2bf(x1.z); b1v.w = f2bf(x1.w);
    ((ushort4*)dst)[lane] = b0;
    ((ushort4*)dst)[lane + 64] = b1v;
    #pragma unroll
    for (int s = 32; s; s >>= 1) d += __shfl_xor(d, s);
    if (lane == 0) {
      if (isf1) s1[row] = d; else s2[row - ROWS1_] = d;
    }
  } else {
    int b2 = blockIdx.x - CVTB_;            // 0..255
    int which = b2 >> 6, tile = b2 & 63;
    const float* W = (which == 0) ? w0 : (which == 1) ? w1 : (which == 2) ? w2 : w3;
    unsigned short* O = (which == 0) ? o0 : (which == 1) ? o1 : (which == 2) ? o2 : o3;
    int k0 = (tile >> 3) * 64, n0 = (tile & 7) * 64;
    #pragma unroll
    for (int i = 0; i < 16; i++) {
      int e = t + i * 256;
      int r = e >> 6, c = e & 63;
      tl[r][c] = W[(size_t)(k0 + r) * D_ + n0 + c];
    }
    __syncthreads();
    #pragma unroll
    for (int i = 0; i < 16; i++) {
      int e = t + i * 256;
      int r = e >> 6, c = e & 63;
      O[(size_t)(n0 + r) * D_ + k0 + c] = f2bf(tl[c][r]);
    }
  }
}

// -------- fused GLU GEMM (both problems, one grid) ---------------------------
// BM=64, BN=128, BK=32; 912 blocks, 4 waves 1x4 (wave tile 64x32).
// 1x4 partition: 4 A + 4 B frag reads/K-step (was 2+8) -> LDS read vol -20%.
__global__ __launch_bounds__(256, 3)
void glu_gemm(const unsigned short* __restrict__ Xb1, const unsigned short* __restrict__ Xb2,
              const unsigned short* __restrict__ W1t_1, const unsigned short* __restrict__ W2t_1,
              const unsigned short* __restrict__ W1t_2, const unsigned short* __restrict__ W2t_2,
              const float* __restrict__ b1_1, const float* __restrict__ b2_1,
              const float* __restrict__ b1_2, const float* __restrict__ b2_2,
              float* __restrict__ o1, float* __restrict__ o0) {
  int nwg = gridDim.x;
  int q = nwg >> 3;                         // nwg % 8 == 0 by construction
  int orig = blockIdx.x;
  int bid = (orig & 7) * q + (orig >> 3);   // XCD-chunked swizzle (bijective)
  const unsigned short *Xb, *W1t, *W2t;
  const float *b1, *b2;
  float* out;
  if (bid < NWG1_) { Xb = Xb1; W1t = W1t_1; W2t = W2t_1; b1 = b1_1; b2 = b2_1; out = o1; }
  else { bid -= NWG1_; Xb = Xb2; W1t = W1t_2; W2t = W2t_2; b1 = b1_2; b2 = b2_2; out = o0; }
  int nt = bid & 3, mt = bid >> 2;
  int m0 = mt * 64, n0 = nt * 128;
  int t = threadIdx.x, lane = t & 63, wave = t >> 6;
  int wc = wave * 32;                       // wave's n-offset (1x4 partition)

  __shared__ alignas(16) unsigned short Xs[2][2048];      // [64][32]
  __shared__ alignas(16) unsigned short Ws[2][2][4096];   // [mat][128][32]

  auto stage = [&](int buf, int k0) {
    {
      int c = t;                                // 256 chunks of 16B: X tile
      const unsigned short* g = Xb + (size_t)(m0 + (c >> 2)) * D_ + k0 + (c & 3) * 8;
      unsigned short* l = &Xs[buf][(size_t)wave * 512];
      __builtin_amdgcn_global_load_lds((const __attribute__((address_space(1))) unsigned int*)g,
                                       (__attribute__((address_space(3))) unsigned int*)l,
                                       16, 0, 0);
    }
    #pragma unroll
    for (int w = 0; w < 2; w++) {
      const unsigned short* Wt = w ? W2t : W1t;
      #pragma unroll
      for (int i = 0; i < 2; i++) {
        int c = t + i * 256;                    // 512 chunks: W tile
        const unsigned short* g = Wt + (size_t)(n0 + (c >> 2)) * D_ + k0 + (c & 3) * 8;
        unsigned short* l = &Ws[buf][w][(size_t)(wave * 64 + i * 256) * 8];
        __builtin_amdgcn_global_load_lds((const __attribute__((address_space(1))) unsigned int*)g,
                                         (__attribute__((address_space(3))) unsigned int*)l,
                                         16, 0, 0);
      }
    }
  };

  f32x4 acc1[4][2], acc2[4][2];
  #pragma unroll
  for (int i = 0; i < 4; i++)
    #pragma unroll
    for (int j = 0; j < 2; j++) { acc1[i][j] = (f32x4)(0.f); acc2[i][j] = (f32x4)(0.f); }

  stage(0, 0);
  int cur = 0;
  int arow = lane & 15, ak = (lane >> 4) * 8;
  for (int ks = 0; ks < 16; ++ks) {
    __syncthreads();
    if (ks < 15) stage(cur ^ 1, (ks + 1) * 32);
    short8 a[4], bf1[2], bf2[2];
    #pragma unroll
    for (int mf = 0; mf < 4; mf++)
      a[mf] = *(const short8*)&Xs[cur][(mf * 16 + arow) * 32 + ak];
    #pragma unroll
    for (int nf = 0; nf < 2; nf++) {
      bf1[nf] = *(const short8*)&Ws[cur][0][(wc + nf * 16 + arow) * 32 + ak];
      bf2[nf] = *(const short8*)&Ws[cur][1][(wc + nf * 16 + arow) * 32 + ak];
    }
    #pragma unroll
    for (int mf = 0; mf < 4; mf++)
      #pragma unroll
      for (int nf = 0; nf < 2; nf++) {
        acc1[mf][nf] = __builtin_amdgcn_mfma_f32_16x16x32_bf16(a[mf], bf1[nf], acc1[mf][nf], 0, 0, 0);
        acc2[mf][nf] = __builtin_amdgcn_mfma_f32_16x16x32_bf16(a[mf], bf2[nf], acc2[mf][nf], 0, 0, 0);
      }
    cur ^= 1;
  }

  // epilogue: C/D layout col=lane&15, row=(lane>>4)*4+r  [m89-verified]
  int crow = (lane >> 4) * 4, ccol = lane & 15;
  #pragma unroll
  for (int mf = 0; mf < 4; mf++) {
    #pragma unroll
    for (int nf = 0; nf < 2; nf++) {
      int col = n0 + wc + nf * 16 + ccol;
      float bb1 = b1[col], bb2 = b2[col];
      #pragma unroll
      for (int r = 0; r < 4; r++) {
        int row = m0 + mf * 16 + crow + r;
        float z1 = acc1[mf][nf][r] + bb1;
        float z2 = acc2[mf][nf][r] + bb2;
        float th = 1.f - 2.f / (__expf(2.f * z1) + 1.f);
        float sg = 1.f / (1.f + __expf(-z2));
        out[(size_t)row * D_ + col] = th * sg;
      }
    }
  }
}

// ---- fhat_fused: softmax + LDS transpose + MFMA, out0 += att @ f1 -----------
// grid = n(64) x dq(8) = 512 blocks, 4 waves. Block handles d = dq*64..+63.
// LDS 50.7KB -> ~3 blocks/CU capacity (better latency hiding than r8's 84.5KB).
__global__ __launch_bounds__(256)
void fhat_fused(const float* __restrict__ s1, const float* __restrict__ s2,
                const float* __restrict__ b_att,
                const unsigned short* __restrict__ f1b,
                float* __restrict__ att, float* __restrict__ out0) {
  int n = blockIdx.x >> 3, dq = blockIdx.x & 7;
  int d0 = dq * 64;
  int t = threadIdx.x, lane = t & 63, wave = t >> 6;
  __shared__ unsigned short Ps[32 * BSTR];    // 16.9 KB
  __shared__ unsigned short Bs[64 * BSTR];    // 33.8 KB

  // Phase B1: zero-pad Bs l in [196, 264)
  for (int e = t; e < 64 * 17; e += 256) {
    int d = e / 17, qq = e % 17;
    ushort4 z; z.x = 0; z.y = 0; z.z = 0; z.w = 0;
    *(ushort4*)&Bs[d * BSTR + 196 + qq * 4] = z;
  }
  // Phase B2: transposed stage of f1b[n][l][d0..d0+63]
  {
    int c4 = t & 15;            // d-group of 4
    int lr = t >> 4;            // 0..15
    #pragma unroll
    for (int i = 0; i < 13; i++) {
      int l = i * 16 + lr;
      if (l < L_) {
        ushort4 v = *(const ushort4*)&f1b[((size_t)n * L_ + l) * D_ + d0 + c4 * 4];
        Bs[(c4 * 4 + 0) * BSTR + l] = v.x;
        Bs[(c4 * 4 + 1) * BSTR + l] = v.y;
        Bs[(c4 * 4 + 2) * BSTR + l] = v.z;
        Bs[(c4 * 4 + 3) * BSTR + l] = v.w;
      }
    }
  }
  // Phase A: softmax for this n (8 lanes per row; rows t = wave*8 + lane/8)
  {
    int trow = wave * 8 + (lane >> 3);
    int j = lane & 7;
    float s2v = s2[n * T_ + trow] + b_att[0];
    const float* s1n = s1 + (size_t)n * L_;
    float v[25];
    float mx = -1e30f;
    #pragma unroll
    for (int i = 0; i < 25; i++) {
      int l = j + 8 * i;
      v[i] = (l < L_) ? (s1n[l] + s2v) : -1e30f;
      mx = fmaxf(mx, v[i]);
    }
    mx = fmaxf(mx, __shfl_xor(mx, 1));
    mx = fmaxf(mx, __shfl_xor(mx, 2));
    mx = fmaxf(mx, __shfl_xor(mx, 4));
    float sum = 0.f;
    #pragma unroll
    for (int i = 0; i < 25; i++) { v[i] = __expf(v[i] - mx); sum += v[i]; }
    sum += __shfl_xor(sum, 1);
    sum += __shfl_xor(sum, 2);
    sum += __shfl_xor(sum, 4);
    float inv = 1.f / sum;
    float* an = att + ((size_t)n * T_ + trow) * L_;
    #pragma unroll
    for (int i = 0; i < 32; i++) {            // l = j+8i covers 0..255
      int l = j + 8 * i;
      float p = (i < 25) ? v[i] * inv : 0.f;
      bool valid = l < L_;
      Ps[trow * BSTR + l] = valid ? f2bf(p) : (unsigned short)0;
      if (dq == 0 && valid) an[l] = p;
    }
  }
  __syncthreads();

  // Phase C: MFMA  C[t][d] += sum_l P[t][l] * Bs[d][l]; wave owns 16 d-cols
  int d0w = wave * 16;
  int arow = lane & 15, ak = (lane >> 4) * 8;
  f32x4 acc[2];
  acc[0] = (f32x4)(0.f); acc[1] = (f32x4)(0.f);
  #pragma unroll 2
  for (int kk = 0; kk < 8; kk++) {
    int k0 = kk * 32;
    short8 a[2], b;
    #pragma unroll
    for (int mt = 0; mt < 2; mt++)
      a[mt] = *(const short8*)&Ps[(mt * 16 + arow) * BSTR + k0 + ak];
    b = *(const short8*)&Bs[(d0w + arow) * BSTR + k0 + ak];
    #pragma unroll
    for (int mt = 0; mt < 2; mt++)
      acc[mt] = __builtin_amdgcn_mfma_f32_16x16x32_bf16(a[mt], b, acc[mt], 0, 0, 0);
  }
  int crow = (lane >> 4) * 4, ccol = lane & 15;
  int d = d0 + d0w + ccol;
  #pragma unroll
  for (int mt = 0; mt < 2; mt++) {
    #pragma unroll
    for (int r = 0; r < 4; r++) {
      int tt = mt * 16 + crow + r;
      size_t idx = ((size_t)n * T_ + tt) * D_ + d;
      out0[idx] += acc[mt][r];
    }
  }
}

extern "C" void kernel_launch(void* const* d_in, const int* in_sizes, int n_in,
                              void* d_out, int out_size, void* d_ws, size_t ws_size,
                              hipStream_t stream) {
  const float* f1    = (const float*)d_in[0];
  const float* f2    = (const float*)d_in[1];
  const float* w_att = (const float*)d_in[2];
  const float* b_att = (const float*)d_in[3];
  const float* n1w1  = (const float*)d_in[4];
  const float* n1b1  = (const float*)d_in[5];
  const float* n1w2  = (const float*)d_in[6];
  const float* n1b2  = (const float*)d_in[7];
  const float* n2w1  = (const float*)d_in[8];
  const float* n2b1  = (const float*)d_in[9];
  const float* n2w2  = (const float*)d_in[10];
  const float* n2b2  = (const float*)d_in[11];

  float* out0 = (float*)d_out;                        // [64][32][512]
  float* out1 = out0 + (size_t)N_ * T_ * D_;          // [64][196][512]
  float* att  = out1 + (size_t)N_ * L_ * D_;          // [64][32][196]

  char* ws = (char*)d_ws;
  auto alloc = [&](size_t bytes) { char* p = ws; ws += (bytes + 255) & ~(size_t)255; return p; };
  unsigned short* f1b   = (unsigned short*)alloc((size_t)ROWS1_ * D_ * 2);
  unsigned short* f2b   = (unsigned short*)alloc((size_t)ROWS2_ * D_ * 2);
  unsigned short* w1t_1 = (unsigned short*)alloc((size_t)D_ * D_ * 2);
  unsigned short* w2t_1 = (unsigned short*)alloc((size_t)D_ * D_ * 2);
  unsigned short* w1t_2 = (unsigned short*)alloc((size_t)D_ * D_ * 2);
  unsigned short* w2t_2 = (unsigned short*)alloc((size_t)D_ * D_ * 2);
  float* s1 = (float*)alloc((size_t)ROWS1_ * 4);
  float* s2 = (float*)alloc((size_t)ROWS2_ * 4);

  prep<<<CVTB_ + 256, 256, 0, stream>>>(f1, f2, w_att, n1w1, n1w2, n2w1, n2w2,
                                        f1b, f2b, s1, s2,
                                        w1t_1, w2t_1, w1t_2, w2t_2);
  glu_gemm<<<NWG1_ + NWG2_, 256, 0, stream>>>(f1b, f2b, w1t_1, w2t_1, w1t_2, w2t_2,
                                              n1b1, n1b2, n2b1, n2b2, out1, out0);
  fhat_fused<<<N_ * 8, 256, 0, stream>>>(s1, s2, b_att, f1b, att, out0);
}